// Round 9
// baseline (205.226 us; speedup 1.0000x reference)
//
#include <hip/hip_runtime.h>

// MaskLoss r9: DECISIVE ABLATION round (accepts temporary regression).
//   kD_noat (1024 blocks, ALL images): incumbent kA pixel path with the ONE
//       ds_add_u32 replaced by asm-volatile keeps (no DCE; gray/quantize/pack
//       all live; minmax/sr2/border outputs real). Duration = kA-minus-atomic.
//   kA_full (1024 blocks): incumbent (control + real histogram).
//   kB_all: unchanged.
// Readout: D1 = total_dur - 183.6us baseline. D1>=45 -> load/compute envelope;
// D1<=20 -> LDS atomic is the hidden ~40us; ~30 -> both.

constexpr int NB   = 2048;       // histogram bins (u16 >> 5)
constexpr int NPIX = 65536;      // 256*256
constexpr int KM_ITERS = 20;
constexpr float QINV = 1.0f / 65536.0f;    // u16 -> gray
constexpr float BINW = 1.0f / 2048.0f;     // bin width in gray units
constexpr unsigned CNT1   = 1u << 19;      // one count in packed u32
constexpr unsigned SVMASK = CNT1 - 1;      // 19-bit sr-sum field (q = sv*64)

// ws byte offsets
constexpr size_t OFF_HIST = 0;                   // 128*2048 u32 = 1 MB (memset 0)
constexpr size_t OFF_MMN  = 1048576;             // 1024 u32 per-block min
constexpr size_t OFF_MMX  = OFF_MMN + 4096;      // 1024 u32 per-block max
constexpr size_t OFF_SR2  = OFF_MMX + 4096;      // 1024 f32 per-block sum(sr^2)
constexpr size_t OFF_ACC  = OFF_SR2 + 4096;      // f32 acc @+0, u32 done @+4
constexpr size_t OFF_BG   = OFF_ACC + 4096;      // 128*1024 u16 border grays (256 KB)
constexpr size_t MEMSET_BYTES = 1048576;         // hist only

__device__ __forceinline__ float waveSumF(float v) {
#pragma unroll
    for (int off = 32; off > 0; off >>= 1) v += __shfl_down(v, off, 64);
    return v;
}
__device__ __forceinline__ unsigned waveMinU(unsigned v) {
#pragma unroll
    for (int off = 32; off > 0; off >>= 1) v = min(v, (unsigned)__shfl_down((int)v, off, 64));
    return v;
}
__device__ __forceinline__ unsigned waveMaxU(unsigned v) {
#pragma unroll
    for (int off = 32; off > 0; off >>= 1) v = max(v, (unsigned)__shfl_down((int)v, off, 64));
    return v;
}

__device__ __forceinline__ void blockTail(
        int blk, int tid, int lane, int wid, float sq, unsigned umn, unsigned umx,
        unsigned* smn, unsigned* smx, float* ssq,
        unsigned* __restrict__ mmn, unsigned* __restrict__ mmx,
        float* __restrict__ bsr2) {
    sq = waveSumF(sq); umn = waveMinU(umn); umx = waveMaxU(umx);
    if (lane == 0) { ssq[wid] = sq; smn[wid] = umn; smx[wid] = umx; }
    __syncthreads();
    if (tid == 0) {
        float SQ = 0.0f; unsigned MN = 65535u, MX = 0u;
#pragma unroll
        for (int w = 0; w < 8; ++w) {
            SQ += ssq[w]; MN = min(MN, smn[w]); MX = max(MX, smx[w]);
        }
        bsr2[blk] = SQ; mmn[blk] = MN; mmx[blk] = MX;
    }
}

// ---- [D-noat] incumbent path, atomic replaced by asm-keep (ALL images) -----
__global__ __launch_bounds__(512) void kD_noat(
        const float* __restrict__ hr, const float* __restrict__ sr,
        unsigned* __restrict__ mmn, unsigned* __restrict__ mmx,
        float* __restrict__ bsr2, ushort* __restrict__ bg) {
    const int blk = blockIdx.x, img = blk >> 3, part = blk & 7;
    const int tid = threadIdx.x, lane = tid & 63, wid = tid >> 6;

    __shared__ unsigned smn[8], smx[8];
    __shared__ float    ssq[8];

    const float* rr = hr + (size_t)img * 3 * NPIX;
    const float* gg = rr + NPIX;
    const float* bb = gg + NPIX;
    const float* sp = sr + (size_t)img * NPIX;
    ushort* bgp = bg + (size_t)img * 1024;

    const int p0 = part * 8192 + tid * 4;
    unsigned umn = 65535u, umx = 0u;
    float sq = 0.0f;
#pragma unroll
    for (int i = 0; i < 4; ++i) {
        const int p = p0 + i * 2048;
        float4 r4 = *(const float4*)(rr + p);
        float4 g4 = *(const float4*)(gg + p);
        float4 b4 = *(const float4*)(bb + p);
        float4 s4 = *(const float4*)(sp + p);
        const float x[4] = { (r4.x + g4.x + b4.x) * (1.0f / 3.0f),
                             (r4.y + g4.y + b4.y) * (1.0f / 3.0f),
                             (r4.z + g4.z + b4.z) * (1.0f / 3.0f),
                             (r4.w + g4.w + b4.w) * (1.0f / 3.0f) };
        const float sv[4] = { s4.x, s4.y, s4.z, s4.w };
        unsigned u[4];
#pragma unroll
        for (int j = 0; j < 4; ++j) {
            unsigned uu = (unsigned)(x[j] * 65536.0f);
            uu = min(uu, 65535u);
            u[j] = uu;
            umn = min(umn, uu); umx = max(umx, uu);
            unsigned q = (unsigned)(sv[j] * 64.0f + 0.5f);
            q = min(q, 63u);
            const unsigned bin = uu >> 5;
            const unsigned pv = CNT1 + q;
            asm volatile("" :: "v"(bin), "v"(pv));   // keep bin+pack live, NO atomic
            sq += sv[j] * sv[j];
        }
        const int row = p >> 8, colb = p & 255;
        if (row == 0) {
            ushort4 qq; qq.x = (ushort)u[0]; qq.y = (ushort)u[1];
            qq.z = (ushort)u[2]; qq.w = (ushort)u[3];
            *(ushort4*)(bgp + colb) = qq;
        }
        if (row == 255) {
            ushort4 qq; qq.x = (ushort)u[0]; qq.y = (ushort)u[1];
            qq.z = (ushort)u[2]; qq.w = (ushort)u[3];
            *(ushort4*)(bgp + 256 + colb) = qq;
        }
        if (colb == 0)   bgp[512 + row] = (ushort)u[0];
        if (colb == 252) bgp[768 + row] = (ushort)u[3];
    }
    __syncthreads();
    blockTail(blk, tid, lane, wid, sq, umn, umx, smn, smx, ssq, mmn, mmx, bsr2);
}

// ---- [A-full] incumbent: single 8KB LDS hist + flush (ALL images) ----------
__global__ __launch_bounds__(512) void kA_full(
        const float* __restrict__ hr, const float* __restrict__ sr,
        unsigned* __restrict__ hist,
        unsigned* __restrict__ mmn, unsigned* __restrict__ mmx,
        float* __restrict__ bsr2, ushort* __restrict__ bg,
        float* __restrict__ acc, unsigned* __restrict__ done) {
    const int blk = blockIdx.x, img = blk >> 3, part = blk & 7;
    const int tid = threadIdx.x, lane = tid & 63, wid = tid >> 6;

    __shared__ unsigned hc[NB];     // 8 KB: packed {count<<19 | sv_q6}
    __shared__ unsigned smn[8], smx[8];
    __shared__ float    ssq[8];
    for (int j = tid; j < NB; j += 512) hc[j] = 0u;
    if (blk == 0 && tid == 0) { *acc = 0.0f; *done = 0u; }   // ticket init (pre-kB)
    __syncthreads();

    const float* rr = hr + (size_t)img * 3 * NPIX;
    const float* gg = rr + NPIX;
    const float* bb = gg + NPIX;
    const float* sp = sr + (size_t)img * NPIX;
    ushort* bgp = bg + (size_t)img * 1024;

    const int p0 = part * 8192 + tid * 4;
    unsigned umn = 65535u, umx = 0u;
    float sq = 0.0f;
#pragma unroll
    for (int i = 0; i < 4; ++i) {
        const int p = p0 + i * 2048;
        float4 r4 = *(const float4*)(rr + p);
        float4 g4 = *(const float4*)(gg + p);
        float4 b4 = *(const float4*)(bb + p);
        float4 s4 = *(const float4*)(sp + p);
        const float x[4] = { (r4.x + g4.x + b4.x) * (1.0f / 3.0f),
                             (r4.y + g4.y + b4.y) * (1.0f / 3.0f),
                             (r4.z + g4.z + b4.z) * (1.0f / 3.0f),
                             (r4.w + g4.w + b4.w) * (1.0f / 3.0f) };
        const float sv[4] = { s4.x, s4.y, s4.z, s4.w };
        unsigned u[4];
#pragma unroll
        for (int j = 0; j < 4; ++j) {
            unsigned uu = (unsigned)(x[j] * 65536.0f);
            uu = min(uu, 65535u);
            u[j] = uu;
            umn = min(umn, uu); umx = max(umx, uu);
            unsigned q = (unsigned)(sv[j] * 64.0f + 0.5f);
            q = min(q, 63u);
            atomicAdd(&hc[uu >> 5], CNT1 + q);   // the ONE ds_add_u32 / pixel
            sq += sv[j] * sv[j];
        }
        const int row = p >> 8, colb = p & 255;
        if (row == 0) {
            ushort4 qq; qq.x = (ushort)u[0]; qq.y = (ushort)u[1];
            qq.z = (ushort)u[2]; qq.w = (ushort)u[3];
            *(ushort4*)(bgp + colb) = qq;
        }
        if (row == 255) {
            ushort4 qq; qq.x = (ushort)u[0]; qq.y = (ushort)u[1];
            qq.z = (ushort)u[2]; qq.w = (ushort)u[3];
            *(ushort4*)(bgp + 256 + colb) = qq;
        }
        if (colb == 0)   bgp[512 + row] = (ushort)u[0];
        if (colb == 252) bgp[768 + row] = (ushort)u[3];
    }
    __syncthreads();

    unsigned* gh = hist + (size_t)img * NB;
    for (int j = tid; j < NB; j += 512) {
        const unsigned v = hc[j];
        if (v) atomicAdd(&gh[j], v);
    }
    blockTail(blk, tid, lane, wid, sq, umn, umx, smn, smx, ssq, mmn, mmx, bsr2);
}

// ---- [B] per-image: unpack + scan + Lloyd + MSE + exact vote + reduce ------
__global__ __launch_bounds__(256) void kB_all(
        const unsigned* __restrict__ mmn, const unsigned* __restrict__ mmx,
        const float* __restrict__ bsr2, const ushort* __restrict__ bg,
        const unsigned* __restrict__ hist,
        float* __restrict__ acc, unsigned* __restrict__ done,
        float* __restrict__ out) {
    const int img = blockIdx.x, tid = threadIdx.x;
    const int lane = tid & 63, wid = tid >> 6;
    __shared__ float sN[NB + 1], sS[NB + 1], sV[NB + 1];
    __shared__ float tN[256], tS[256], tV[256];
    __shared__ float bres[4];           // {t, hi, mse0, mse1}
    __shared__ float4 sB4[4];

    const int base = tid * 8;
    const unsigned* gh = hist + (size_t)img * NB + base;
    const uint4 p0 = *(const uint4*)gh;
    const uint4 p1 = *(const uint4*)(gh + 4);
    const unsigned pk[8] = { p0.x, p0.y, p0.z, p0.w, p1.x, p1.y, p1.z, p1.w };
    float n8[8], s8[8], v8[8];
#pragma unroll
    for (int u = 0; u < 8; ++u) {
        const float c = (float)(pk[u] >> 19);
        n8[u] = c;
        s8[u] = c * (((float)(base + u) + 0.484375f) * BINW);  // mean u in bin
        v8[u] = (float)(pk[u] & SVMASK) * (1.0f / 64.0f);
    }

    float accN = 0.0f, accS = 0.0f, accV = 0.0f;
#pragma unroll
    for (int u = 7; u >= 0; --u) {
        accN += n8[u]; n8[u] = accN;
        accS += s8[u]; s8[u] = accS;
        accV += v8[u]; v8[u] = accV;
    }
    tN[tid] = accN; tS[tid] = accS; tV[tid] = accV;
    __syncthreads();
    for (int off = 1; off < 256; off <<= 1) {
        float aNN = 0.0f, aSS = 0.0f, aVV = 0.0f;
        if (tid + off < 256) { aNN = tN[tid + off]; aSS = tS[tid + off]; aVV = tV[tid + off]; }
        __syncthreads();
        tN[tid] += aNN; tS[tid] += aSS; tV[tid] += aVV;
        __syncthreads();
    }
    const float exN = (tid < 255) ? tN[tid + 1] : 0.0f;
    const float exS = (tid < 255) ? tS[tid + 1] : 0.0f;
    const float exV = (tid < 255) ? tV[tid + 1] : 0.0f;
#pragma unroll
    for (int u = 0; u < 8; ++u) {
        sN[base + u] = n8[u] + exN;
        sS[base + u] = s8[u] + exS;
        sV[base + u] = v8[u] + exV;
    }
    if (tid == 0) { sN[NB] = 0.0f; sS[NB] = 0.0f; sV[NB] = 0.0f; }
    __syncthreads();

    if (tid == 0) {
        unsigned bmn = 65535u, bmx = 0u;
#pragma unroll
        for (int s = 0; s < 8; ++s) {
            bmn = min(bmn, mmn[img * 8 + s]);
            bmx = max(bmx, mmx[img * 8 + s]);
        }
        float c0f = (float)bmn * QINV;
        float c1f = (float)bmx * QINV;
        const float Stot = sS[0];
        const float Ntot = (float)NPIX;
#pragma unroll 1
        for (int it = 0; it < KM_ITERS; ++it) {
            const float t = 0.5f * (c0f + c1f);
            float n1, s1;
            if (c1f == c0f) { n1 = 0.0f; s1 = 0.0f; }
            else {
                const float f = t * (float)NB;
                int k = (int)floorf(f);
                k = max(0, min(NB - 1, k));
                float frac = (float)(k + 1) - f;             // fraction of bin k above t
                frac = fminf(fmaxf(frac, 0.0f), 1.0f);
                const float cntk = sN[k] - sN[k + 1];
                const float aNt = sN[k + 1] + cntk * frac;   // count of x > t
                const float aSt = sS[k + 1] +
                                  cntk * frac * 0.5f * (t + (float)(k + 1) * BINW);
                if (c1f > c0f) { n1 = aNt; s1 = aSt; }
                else           { n1 = Ntot - aNt; s1 = Stot - aSt; }
            }
            const float c1n = s1 / fmaxf(n1, 1.0f);
            const float c0n = (Stot - s1) / fmaxf(Ntot - n1, 1.0f);
            if (c1n == c1f && c0n == c0f) break;   // exact fixed point
            c0f = c0n; c1f = c1n;
        }

        float Sr2 = 0.0f;
#pragma unroll
        for (int s = 0; s < 8; ++s) Sr2 += bsr2[img * 8 + s];
        const float SvTot = sV[0];

        float tf, hii, n1, s1v;
        if (c1f == c0f) { tf = -1e30f; hii = 0.0f; n1 = 0.0f; s1v = 0.0f; }
        else {
            tf = 0.5f * (c0f + c1f);
            const float f = tf * (float)NB;
            int k = (int)floorf(f);
            k = max(0, min(NB - 1, k));
            float frac = (float)(k + 1) - f;
            frac = fminf(fmaxf(frac, 0.0f), 1.0f);
            const float cntk = sN[k] - sN[k + 1];
            const float aNt = sN[k + 1] + cntk * frac;       // count of x > t
            const float svk = sV[k] - sV[k + 1];
            const float aSv = sV[k + 1] + svk * frac;        // sr-mass above t
            if (c1f > c0f) { hii = 1.0f; n1 = aNt;        s1v = aSv; }
            else           { hii = 0.0f; n1 = Ntot - aNt; s1v = SvTot - aSv; }
        }
        bres[0] = tf; bres[1] = hii;
        bres[2] = Sr2 - 2.0f * s1v + n1;                       // mse, mask as-is
        bres[3] = Sr2 - 2.0f * (SvTot - s1v) + (Ntot - n1);    // mse, mask flipped
    }
    __syncthreads();

    const float tf = bres[0];
    const bool hi = (bres[1] != 0.0f);
    const ushort* bp = bg + (size_t)img * 1024;
    const float x0 = (float)bp[tid]       * QINV;   // row 0, col tid
    const float x1 = (float)bp[256 + tid] * QINV;   // row 255
    const float x2 = (float)bp[512 + tid] * QINV;   // col 0, row tid
    const float x3 = (float)bp[768 + tid] * QINV;   // col 255
    float fr = (hi ? (x0 > tf) : (x0 < tf)) ? 1.0f : 0.0f;
    float lr = (hi ? (x1 > tf) : (x1 < tf)) ? 1.0f : 0.0f;
    float fc = (hi ? (x2 > tf) : (x2 < tf)) ? 1.0f : 0.0f;
    float lc = (hi ? (x3 > tf) : (x3 < tf)) ? 1.0f : 0.0f;
    fr = waveSumF(fr); lr = waveSumF(lr); fc = waveSumF(fc); lc = waveSumF(lc);
    if (lane == 0) sB4[wid] = make_float4(fr, lr, fc, lc);
    __syncthreads();
    if (tid == 0) {
        const float FR = sB4[0].x + sB4[1].x + sB4[2].x + sB4[3].x;
        const float LR = sB4[0].y + sB4[1].y + sB4[2].y + sB4[3].y;
        const float FC = sB4[0].z + sB4[1].z + sB4[2].z + sB4[3].z;
        const float LC = sB4[0].w + sB4[1].w + sB4[2].w + sB4[3].w;
        const int num = (FR > 128.0f) + (LR > 128.0f) + (FC > 128.0f) + (LC > 128.0f);
        const float chosen = (num >= 3) ? bres[3] : bres[2];
        atomicAdd(acc, chosen);
        __threadfence();
        const unsigned old = atomicAdd(done, 1u);
        if (old == 127u) {
            const float tot = atomicAdd(acc, 0.0f);   // all adds happened-before
            out[0] = tot * (1.0f / 8388608.0f);
        }
    }
}

extern "C" void kernel_launch(void* const* d_in, const int* in_sizes, int n_in,
                              void* d_out, int out_size, void* d_ws, size_t ws_size,
                              hipStream_t stream) {
    const float* hr = (const float*)d_in[0];   // [128,3,256,256] f32
    const float* sr = (const float*)d_in[1];   // [128,1,256,256] f32
    float* out = (float*)d_out;

    char* ws = (char*)d_ws;
    unsigned* hist = (unsigned*)(ws + OFF_HIST);
    unsigned* mmn  = (unsigned*)(ws + OFF_MMN);
    unsigned* mmx  = (unsigned*)(ws + OFF_MMX);
    float*    bsr2 = (float*)(ws + OFF_SR2);
    float*    acc  = (float*)(ws + OFF_ACC);
    unsigned* done = (unsigned*)(ws + OFF_ACC + 4);
    ushort*   bg   = (ushort*)(ws + OFF_BG);

    hipMemsetAsync(hist, 0, MEMSET_BYTES, stream);
    kD_noat<<<1024, 512, 0, stream>>>(hr, sr, mmn, mmx, bsr2, bg);
    kA_full<<<1024, 512, 0, stream>>>(hr, sr, hist, mmn, mmx, bsr2, bg, acc, done);
    kB_all <<< 128, 256, 0, stream>>>(mmn, mmx, bsr2, bg, hist, acc, done, out);
}

// Round 10
// 183.098 us; speedup vs baseline: 1.1209x; 1.1209x over previous
//
#include <hip/hip_runtime.h>

// MaskLoss r10: software-pipelined kA (register double-buffer).
// r9 ablation: kA = 22us envelope + 33us DS-atomic/hist machinery, ADDITIVE
// (zero overlap). DS drain (~1 lane-op/cy/CU at 1 atomic/px) is the floor;
// the envelope can hide under it if next-quad loads issue BEFORE current-quad
// atomics. 2-stage reg double-buffer (32 payload VGPRs) + sched_barrier(0x87)
// (VMEM may NOT cross; VALU/SALU/DS may) pins the order. launch_bounds(512,4)
// caps VGPR<=128 (no spills). Numerics byte-identical to 183.6us incumbent:
// packed u32 {count<<19|sv_q6} ds_add, exact counts -> Lloyd t bit-identical,
// EXACT border vote, closed-form dual MSE.

constexpr int NB   = 2048;       // histogram bins (u16 >> 5)
constexpr int NPIX = 65536;      // 256*256
constexpr int KM_ITERS = 20;
constexpr float QINV = 1.0f / 65536.0f;    // u16 -> gray
constexpr float BINW = 1.0f / 2048.0f;     // bin width in gray units
constexpr unsigned CNT1   = 1u << 19;      // one count in packed u32
constexpr unsigned SVMASK = CNT1 - 1;      // 19-bit sr-sum field (q = sv*64)

// ws byte offsets
constexpr size_t OFF_HIST = 0;                   // 128*2048 u32 = 1 MB (memset 0)
constexpr size_t OFF_MMN  = 1048576;             // 1024 u32 per-block min
constexpr size_t OFF_MMX  = OFF_MMN + 4096;      // 1024 u32 per-block max
constexpr size_t OFF_SR2  = OFF_MMX + 4096;      // 1024 f32 per-block sum(sr^2)
constexpr size_t OFF_ACC  = OFF_SR2 + 4096;      // f32 acc @+0, u32 done @+4
constexpr size_t OFF_BG   = OFF_ACC + 4096;      // 128*1024 u16 border grays (256 KB)
constexpr size_t MEMSET_BYTES = 1048576;         // hist only

__device__ __forceinline__ float waveSumF(float v) {
#pragma unroll
    for (int off = 32; off > 0; off >>= 1) v += __shfl_down(v, off, 64);
    return v;
}
__device__ __forceinline__ unsigned waveMinU(unsigned v) {
#pragma unroll
    for (int off = 32; off > 0; off >>= 1) v = min(v, (unsigned)__shfl_down((int)v, off, 64));
    return v;
}
__device__ __forceinline__ unsigned waveMaxU(unsigned v) {
#pragma unroll
    for (int off = 32; off > 0; off >>= 1) v = max(v, (unsigned)__shfl_down((int)v, off, 64));
    return v;
}

// ---- [A] pipelined: loads(i+1) issued before atomics(i) --------------------
__global__ __launch_bounds__(512, 4) void kA_hist(
        const float* __restrict__ hr, const float* __restrict__ sr,
        unsigned* __restrict__ hist,
        unsigned* __restrict__ mmn, unsigned* __restrict__ mmx,
        float* __restrict__ bsr2, ushort* __restrict__ bg,
        float* __restrict__ acc, unsigned* __restrict__ done) {
    const int blk = blockIdx.x, img = blk >> 3, part = blk & 7;
    const int tid = threadIdx.x, lane = tid & 63, wid = tid >> 6;

    __shared__ unsigned hc[NB];     // 8 KB: packed {count<<19 | sv_q6}
    __shared__ unsigned smn[8], smx[8];
    __shared__ float    ssq[8];
    for (int j = tid; j < NB; j += 512) hc[j] = 0u;
    if (blk == 0 && tid == 0) { *acc = 0.0f; *done = 0u; }   // ticket init (pre-kB)
    __syncthreads();

    const float* rr = hr + (size_t)img * 3 * NPIX;
    const float* gg = rr + NPIX;
    const float* bb = gg + NPIX;
    const float* sp = sr + (size_t)img * NPIX;
    ushort* bgp = bg + (size_t)img * 1024;

    const int p0 = part * 8192 + tid * 4;     // 4 quads at stride 2048
    unsigned umn = 65535u, umx = 0u;
    float sq = 0.0f;

    float4 Ra, Ga, Ba, Sa, Rb, Gb, Bb, Sb;

#define LOADQ(Rx, Gx, Bx, Sx, P)                                              \
    do {                                                                      \
        Rx = *(const float4*)(rr + (P));                                      \
        Gx = *(const float4*)(gg + (P));                                      \
        Bx = *(const float4*)(bb + (P));                                      \
        Sx = *(const float4*)(sp + (P));                                      \
    } while (0)

#define PROCQ(Rx, Gx, Bx, Sx, P)                                              \
    do {                                                                      \
        const float x0 = (Rx.x + Gx.x + Bx.x) * (1.0f / 3.0f);                \
        const float x1 = (Rx.y + Gx.y + Bx.y) * (1.0f / 3.0f);                \
        const float x2 = (Rx.z + Gx.z + Bx.z) * (1.0f / 3.0f);                \
        const float x3 = (Rx.w + Gx.w + Bx.w) * (1.0f / 3.0f);                \
        unsigned u0 = min((unsigned)(x0 * 65536.0f), 65535u);                 \
        unsigned u1 = min((unsigned)(x1 * 65536.0f), 65535u);                 \
        unsigned u2 = min((unsigned)(x2 * 65536.0f), 65535u);                 \
        unsigned u3 = min((unsigned)(x3 * 65536.0f), 65535u);                 \
        umn = min(umn, min(min(u0, u1), min(u2, u3)));                        \
        umx = max(umx, max(max(u0, u1), max(u2, u3)));                        \
        unsigned q0 = min((unsigned)(Sx.x * 64.0f + 0.5f), 63u);              \
        unsigned q1 = min((unsigned)(Sx.y * 64.0f + 0.5f), 63u);              \
        unsigned q2 = min((unsigned)(Sx.z * 64.0f + 0.5f), 63u);              \
        unsigned q3 = min((unsigned)(Sx.w * 64.0f + 0.5f), 63u);              \
        atomicAdd(&hc[u0 >> 5], CNT1 + q0);                                   \
        atomicAdd(&hc[u1 >> 5], CNT1 + q1);                                   \
        atomicAdd(&hc[u2 >> 5], CNT1 + q2);                                   \
        atomicAdd(&hc[u3 >> 5], CNT1 + q3);                                   \
        sq += Sx.x * Sx.x + Sx.y * Sx.y + Sx.z * Sx.z + Sx.w * Sx.w;          \
        const int row = (P) >> 8, colb = (P) & 255;                           \
        if (row == 0) {                                                       \
            ushort4 qq; qq.x = (ushort)u0; qq.y = (ushort)u1;                 \
            qq.z = (ushort)u2; qq.w = (ushort)u3;                             \
            *(ushort4*)(bgp + colb) = qq;                                     \
        }                                                                     \
        if (row == 255) {                                                     \
            ushort4 qq; qq.x = (ushort)u0; qq.y = (ushort)u1;                 \
            qq.z = (ushort)u2; qq.w = (ushort)u3;                             \
            *(ushort4*)(bgp + 256 + colb) = qq;                               \
        }                                                                     \
        if (colb == 0)   bgp[512 + row] = (ushort)u0;                         \
        if (colb == 252) bgp[768 + row] = (ushort)u3;                         \
    } while (0)

    // prologue: quad 0 -> A
    LOADQ(Ra, Ga, Ba, Sa, p0);
    // iter 0: issue quad1 -> B, then process A (vmcnt waits only on A)
    LOADQ(Rb, Gb, Bb, Sb, p0 + 2048);
    __builtin_amdgcn_sched_barrier(0x87);     // VMEM may not cross
    PROCQ(Ra, Ga, Ba, Sa, p0);
    // iter 1: issue quad2 -> A, process B
    LOADQ(Ra, Ga, Ba, Sa, p0 + 4096);
    __builtin_amdgcn_sched_barrier(0x87);
    PROCQ(Rb, Gb, Bb, Sb, p0 + 2048);
    // iter 2: issue quad3 -> B, process A
    LOADQ(Rb, Gb, Bb, Sb, p0 + 6144);
    __builtin_amdgcn_sched_barrier(0x87);
    PROCQ(Ra, Ga, Ba, Sa, p0 + 4096);
    // iter 3: process B
    PROCQ(Rb, Gb, Bb, Sb, p0 + 6144);

#undef LOADQ
#undef PROCQ
    __syncthreads();

    // flush LDS hist -> per-image global hist (one u32 atomic per nonempty bin)
    unsigned* gh = hist + (size_t)img * NB;
    for (int j = tid; j < NB; j += 512) {
        const unsigned v = hc[j];
        if (v) atomicAdd(&gh[j], v);
    }

    sq = waveSumF(sq); umn = waveMinU(umn); umx = waveMaxU(umx);
    if (lane == 0) { ssq[wid] = sq; smn[wid] = umn; smx[wid] = umx; }
    __syncthreads();
    if (tid == 0) {
        float SQ = 0.0f; unsigned MN = 65535u, MX = 0u;
#pragma unroll
        for (int w = 0; w < 8; ++w) {
            SQ += ssq[w]; MN = min(MN, smn[w]); MX = max(MX, smx[w]);
        }
        bsr2[blk] = SQ; mmn[blk] = MN; mmx[blk] = MX;
    }
}

// ---- [B] per-image: unpack + scan + Lloyd + MSE + exact vote + reduce ------
__global__ __launch_bounds__(256) void kB_all(
        const unsigned* __restrict__ mmn, const unsigned* __restrict__ mmx,
        const float* __restrict__ bsr2, const ushort* __restrict__ bg,
        const unsigned* __restrict__ hist,
        float* __restrict__ acc, unsigned* __restrict__ done,
        float* __restrict__ out) {
    const int img = blockIdx.x, tid = threadIdx.x;
    const int lane = tid & 63, wid = tid >> 6;
    __shared__ float sN[NB + 1], sS[NB + 1], sV[NB + 1];
    __shared__ float tN[256], tS[256], tV[256];
    __shared__ float bres[4];           // {t, hi, mse0, mse1}
    __shared__ float4 sB4[4];

    const int base = tid * 8;
    const unsigned* gh = hist + (size_t)img * NB + base;
    const uint4 p0 = *(const uint4*)gh;
    const uint4 p1 = *(const uint4*)(gh + 4);
    const unsigned pk[8] = { p0.x, p0.y, p0.z, p0.w, p1.x, p1.y, p1.z, p1.w };
    float n8[8], s8[8], v8[8];
#pragma unroll
    for (int u = 0; u < 8; ++u) {
        const float c = (float)(pk[u] >> 19);
        n8[u] = c;
        s8[u] = c * (((float)(base + u) + 0.484375f) * BINW);  // mean u in bin
        v8[u] = (float)(pk[u] & SVMASK) * (1.0f / 64.0f);
    }

    float accN = 0.0f, accS = 0.0f, accV = 0.0f;
#pragma unroll
    for (int u = 7; u >= 0; --u) {
        accN += n8[u]; n8[u] = accN;
        accS += s8[u]; s8[u] = accS;
        accV += v8[u]; v8[u] = accV;
    }
    tN[tid] = accN; tS[tid] = accS; tV[tid] = accV;
    __syncthreads();
    for (int off = 1; off < 256; off <<= 1) {
        float aNN = 0.0f, aSS = 0.0f, aVV = 0.0f;
        if (tid + off < 256) { aNN = tN[tid + off]; aSS = tS[tid + off]; aVV = tV[tid + off]; }
        __syncthreads();
        tN[tid] += aNN; tS[tid] += aSS; tV[tid] += aVV;
        __syncthreads();
    }
    const float exN = (tid < 255) ? tN[tid + 1] : 0.0f;
    const float exS = (tid < 255) ? tS[tid + 1] : 0.0f;
    const float exV = (tid < 255) ? tV[tid + 1] : 0.0f;
#pragma unroll
    for (int u = 0; u < 8; ++u) {
        sN[base + u] = n8[u] + exN;
        sS[base + u] = s8[u] + exS;
        sV[base + u] = v8[u] + exV;
    }
    if (tid == 0) { sN[NB] = 0.0f; sS[NB] = 0.0f; sV[NB] = 0.0f; }
    __syncthreads();

    if (tid == 0) {
        unsigned bmn = 65535u, bmx = 0u;
#pragma unroll
        for (int s = 0; s < 8; ++s) {
            bmn = min(bmn, mmn[img * 8 + s]);
            bmx = max(bmx, mmx[img * 8 + s]);
        }
        float c0f = (float)bmn * QINV;
        float c1f = (float)bmx * QINV;
        const float Stot = sS[0];
        const float Ntot = (float)NPIX;
#pragma unroll 1
        for (int it = 0; it < KM_ITERS; ++it) {
            const float t = 0.5f * (c0f + c1f);
            float n1, s1;
            if (c1f == c0f) { n1 = 0.0f; s1 = 0.0f; }
            else {
                const float f = t * (float)NB;
                int k = (int)floorf(f);
                k = max(0, min(NB - 1, k));
                float frac = (float)(k + 1) - f;             // fraction of bin k above t
                frac = fminf(fmaxf(frac, 0.0f), 1.0f);
                const float cntk = sN[k] - sN[k + 1];
                const float aNt = sN[k + 1] + cntk * frac;   // count of x > t
                const float aSt = sS[k + 1] +
                                  cntk * frac * 0.5f * (t + (float)(k + 1) * BINW);
                if (c1f > c0f) { n1 = aNt; s1 = aSt; }
                else           { n1 = Ntot - aNt; s1 = Stot - aSt; }
            }
            const float c1n = s1 / fmaxf(n1, 1.0f);
            const float c0n = (Stot - s1) / fmaxf(Ntot - n1, 1.0f);
            if (c1n == c1f && c0n == c0f) break;   // exact fixed point
            c0f = c0n; c1f = c1n;
        }

        float Sr2 = 0.0f;
#pragma unroll
        for (int s = 0; s < 8; ++s) Sr2 += bsr2[img * 8 + s];
        const float SvTot = sV[0];

        float tf, hii, n1, s1v;
        if (c1f == c0f) { tf = -1e30f; hii = 0.0f; n1 = 0.0f; s1v = 0.0f; }
        else {
            tf = 0.5f * (c0f + c1f);
            const float f = tf * (float)NB;
            int k = (int)floorf(f);
            k = max(0, min(NB - 1, k));
            float frac = (float)(k + 1) - f;
            frac = fminf(fmaxf(frac, 0.0f), 1.0f);
            const float cntk = sN[k] - sN[k + 1];
            const float aNt = sN[k + 1] + cntk * frac;       // count of x > t
            const float svk = sV[k] - sV[k + 1];
            const float aSv = sV[k + 1] + svk * frac;        // sr-mass above t
            if (c1f > c0f) { hii = 1.0f; n1 = aNt;        s1v = aSv; }
            else           { hii = 0.0f; n1 = Ntot - aNt; s1v = SvTot - aSv; }
        }
        bres[0] = tf; bres[1] = hii;
        bres[2] = Sr2 - 2.0f * s1v + n1;                       // mse, mask as-is
        bres[3] = Sr2 - 2.0f * (SvTot - s1v) + (Ntot - n1);    // mse, mask flipped
    }
    __syncthreads();

    const float tf = bres[0];
    const bool hi = (bres[1] != 0.0f);
    const ushort* bp = bg + (size_t)img * 1024;
    const float x0 = (float)bp[tid]       * QINV;   // row 0, col tid
    const float x1 = (float)bp[256 + tid] * QINV;   // row 255
    const float x2 = (float)bp[512 + tid] * QINV;   // col 0, row tid
    const float x3 = (float)bp[768 + tid] * QINV;   // col 255
    float fr = (hi ? (x0 > tf) : (x0 < tf)) ? 1.0f : 0.0f;
    float lr = (hi ? (x1 > tf) : (x1 < tf)) ? 1.0f : 0.0f;
    float fc = (hi ? (x2 > tf) : (x2 < tf)) ? 1.0f : 0.0f;
    float lc = (hi ? (x3 > tf) : (x3 < tf)) ? 1.0f : 0.0f;
    fr = waveSumF(fr); lr = waveSumF(lr); fc = waveSumF(fc); lc = waveSumF(lc);
    if (lane == 0) sB4[wid] = make_float4(fr, lr, fc, lc);
    __syncthreads();
    if (tid == 0) {
        const float FR = sB4[0].x + sB4[1].x + sB4[2].x + sB4[3].x;
        const float LR = sB4[0].y + sB4[1].y + sB4[2].y + sB4[3].y;
        const float FC = sB4[0].z + sB4[1].z + sB4[2].z + sB4[3].z;
        const float LC = sB4[0].w + sB4[1].w + sB4[2].w + sB4[3].w;
        const int num = (FR > 128.0f) + (LR > 128.0f) + (FC > 128.0f) + (LC > 128.0f);
        const float chosen = (num >= 3) ? bres[3] : bres[2];
        atomicAdd(acc, chosen);
        __threadfence();
        const unsigned old = atomicAdd(done, 1u);
        if (old == 127u) {
            const float tot = atomicAdd(acc, 0.0f);   // all adds happened-before
            out[0] = tot * (1.0f / 8388608.0f);
        }
    }
}

extern "C" void kernel_launch(void* const* d_in, const int* in_sizes, int n_in,
                              void* d_out, int out_size, void* d_ws, size_t ws_size,
                              hipStream_t stream) {
    const float* hr = (const float*)d_in[0];   // [128,3,256,256] f32
    const float* sr = (const float*)d_in[1];   // [128,1,256,256] f32
    float* out = (float*)d_out;

    char* ws = (char*)d_ws;
    unsigned* hist = (unsigned*)(ws + OFF_HIST);
    unsigned* mmn  = (unsigned*)(ws + OFF_MMN);
    unsigned* mmx  = (unsigned*)(ws + OFF_MMX);
    float*    bsr2 = (float*)(ws + OFF_SR2);
    float*    acc  = (float*)(ws + OFF_ACC);
    unsigned* done = (unsigned*)(ws + OFF_ACC + 4);
    ushort*   bg   = (ushort*)(ws + OFF_BG);

    hipMemsetAsync(hist, 0, MEMSET_BYTES, stream);
    kA_hist<<<1024, 512, 0, stream>>>(hr, sr, hist, mmn, mmx, bsr2, bg, acc, done);
    kB_all <<< 128, 256, 0, stream>>>(mmn, mmx, bsr2, bg, hist, acc, done, out);
}